// Round 9
// baseline (69.788 us; speedup 1.0000x reference)
//
#include <hip/hip_runtime.h>
#include <math.h>

#define TS 64
#define T 64
#define K 256
#define NSEG 4
#define KSEG 64
#define IMG_W 512

// Single fused kernel: 512 blocks x 512 threads, 2 blocks/CU.
//
// Stage (split across all 8 waves -- waves 0-3: mu/cov/opacity -> sA/sB/sR,
// waves 4-7: color -> sCol):
//   alpha_raw = op*exp(-0.5*maha) = exp2(ea*dx^2 + eb*dx*dy + ed*dy^2 + lop)
//   s = -0.5*log2(e)/det: ea=s*d, eb=-s*(b+c), ed=s*a, lop=log2(op)
//   cull radius r^2 = 2*ln(op/0.01)*(a+d): beyond it maha >= d2/(a+d)
//   forces op*exp(-maha/2) <= 0.01 -> clip == 0.01f bit-exactly.
//
// Render: seg = tid>>7 handles k in [seg*64, seg*64+64); wave = 64 cols x
// 4-row band. Far runs never cross segment boundaries, so each wave builds
// its segment's col / k'*col prefix sums with a 64-lane shuffle scan (no
// barriers, no LDS -- replaces R8's 16-barrier Hillis-Steele). The 64-bit
// near-mask comes from one __ballot; far stretches [i,j) (every alpha ==
// 0.01f) collapse to O(1):
//   dC = 0.01*(1-S)*P1 - 1e-4*(Pk' - i'*P1),  dS = 0.01*len.
// Segment combine: C = C_0 + sum_{s>=1}(C_s - S_prev(s)*A_s).
__global__ __launch_bounds__(512, 4) void render_all(
    const float* __restrict__ mu, const float* __restrict__ cov,
    const float* __restrict__ opacity, const float* __restrict__ color,
    const int* __restrict__ tile_idx, float* __restrict__ out) {
  __shared__ float4 sA[K];    // mux, muy, ea, eb
  __shared__ float2 sB[K];    // ed, lop
  __shared__ float4 sCol[K];  // cr, cg, cb, -
  __shared__ float sR[K];     // r2
  __shared__ float sS[NSEG][128][4];
  __shared__ float sD[3][128][4][3];

  int tid = threadIdx.x;
  int blk = blockIdx.x;
  int tile = blk & 63;   // XCD affinity: tile%8 == blk%8
  int chunk = blk >> 6;  // 0..7

  {
    int g = tid & 255;
    int n = tile_idx[tile * K + g];
    if (tid < K) {
      float4 cv = *(const float4*)(cov + 4 * n);  // a,b,c,d
      float2 mm = *(const float2*)(mu + 2 * n);
      float op = opacity[n];
      float det = fmaxf(cv.x * cv.w - cv.y * cv.z, 1e-6f);
      const float LOG2E = 1.4426950408889634f;
      float s = -0.5f * LOG2E / det;
      float lop = log2f(fmaxf(op, 1e-30f));
      sA[g] = make_float4(mm.x, mm.y, s * cv.w, -s * (cv.y + cv.z));
      sB[g] = make_float2(s * cv.x, lop);
      float r2 = 1.3862943611f * (lop + 6.6438561898f) * (cv.x + cv.w);
      sR[g] = r2 * 1.0001f + 1e-3f;
    } else {
      const float* cp = color + 3 * n;
      sCol[g] = make_float4(cp[0], cp[1], cp[2], 0.f);
    }
  }
  __syncthreads();

  int seg = __builtin_amdgcn_readfirstlane(tid >> 7);  // 0..3, wave-uniform
  int pslot = tid & 127;
  int lane = tid & 63;
  int lx = pslot & 63;
  int bnd = __builtin_amdgcn_readfirstlane(chunk * 2 + ((tid >> 6) & 1));
  int ty = tile >> 3, tx = tile & 7;
  int ly0 = bnd * 4;
  float px = (float)(tx * TS + lx) + 0.5f;
  float py0 = (float)(ty * TS + ly0) + 0.5f;
  const int kb = seg * KSEG;

  // Wave-local inclusive scans over this segment's 64 gaussians:
  // icr/icg/icb = prefix of col; jcr/jcg/jcb = prefix of (local k)*col.
  float icr, icg, icb, jcr, jcg, jcb;
  {
    float4 cl = sCol[kb + lane];
    float fl = (float)lane;
    icr = cl.x;
    icg = cl.y;
    icb = cl.z;
    jcr = fl * cl.x;
    jcg = fl * cl.y;
    jcb = fl * cl.z;
    for (int off = 1; off < 64; off <<= 1) {
      float t0 = __shfl_up(icr, off);
      float t1 = __shfl_up(icg, off);
      float t2 = __shfl_up(icb, off);
      float t3 = __shfl_up(jcr, off);
      float t4 = __shfl_up(jcg, off);
      float t5 = __shfl_up(jcb, off);
      if (lane >= off) {
        icr += t0;
        icg += t1;
        icb += t2;
        jcr += t3;
        jcg += t4;
        jcb += t5;
      }
    }
  }
  // Exclusive-prefix accessor for wave-uniform q in [0,64].
#define PFX(v, q) ((q) == 0 ? 0.f : __shfl((v), (q)-1))

  // Near-mask: lane l tests gaussian kb+l against this wave's 64x4 band.
  unsigned long long m;
  {
    float4 Ag = sA[kb + lane];
    float r2 = sR[kb + lane];
    float x0 = tx * TS + 0.5f, x1 = tx * TS + 63.5f;
    float y0 = py0, y1 = py0 + 3.0f;
    float dxm = fmaxf(fmaxf(Ag.x - x1, x0 - Ag.x), 0.f);
    float dym = fmaxf(fmaxf(Ag.y - y1, y0 - Ag.y), 0.f);
    float d2 = fmaf(dxm, dxm, dym * dym);
    m = __ballot(d2 < r2);
  }

  float C[4][3] = {};
  float An[4][3] = {};
  float Af[3] = {0.f, 0.f, 0.f};
  float S[4] = {};

  int i = kb;
  while (true) {
    int j = (m != 0ULL) ? (kb + (int)__builtin_ctzll(m)) : (kb + KSEG);
    if (j > i) {  // far run [i, j): every alpha == 0.01 exactly
      int i2 = i - kb, j2 = j - kb;
      float len = (float)(j2 - i2);
      float P1r = PFX(icr, j2) - PFX(icr, i2);
      float P1g = PFX(icg, j2) - PFX(icg, i2);
      float P1b = PFX(icb, j2) - PFX(icb, i2);
      float fi = (float)i2;
      float Rr = -1e-4f * fmaf(-fi, P1r, PFX(jcr, j2) - PFX(jcr, i2));
      float Rg = -1e-4f * fmaf(-fi, P1g, PFX(jcg, j2) - PFX(jcg, i2));
      float Rb = -1e-4f * fmaf(-fi, P1b, PFX(jcb, j2) - PFX(jcb, i2));
      Af[0] = fmaf(0.01f, P1r, Af[0]);
      Af[1] = fmaf(0.01f, P1g, Af[1]);
      Af[2] = fmaf(0.01f, P1b, Af[2]);
#pragma unroll
      for (int p = 0; p < 4; ++p) {
        float t = fmaf(-0.01f, S[p], 0.01f);  // 0.01*(1 - S_local)
        C[p][0] = fmaf(t, P1r, C[p][0]) + Rr;
        C[p][1] = fmaf(t, P1g, C[p][1]) + Rg;
        C[p][2] = fmaf(t, P1b, C[p][2]) + Rb;
        S[p] = fmaf(0.01f, len, S[p]);
      }
    }
    if (j >= kb + KSEG) break;
    // near gaussian k = j: full math
    float4 A4 = sA[j];
    float2 B2 = sB[j];
    float4 c4 = sCol[j];
    float dx = px - A4.x;
    float tb = A4.w * dx;
    float base = fmaf(A4.z * dx, dx, B2.y);
    float dy = py0 - A4.y;
#pragma unroll
    for (int p = 0; p < 4; ++p) {
      float dyp = dy + (float)p;
      float mm = fmaf(dyp, fmaf(B2.x, dyp, tb), base);
      float al =
          __builtin_amdgcn_fmed3f(__builtin_amdgcn_exp2f(mm), 0.01f, 0.99f);
      float w = fmaf(-al, S[p], al);
      C[p][0] = fmaf(w, c4.x, C[p][0]);
      C[p][1] = fmaf(w, c4.y, C[p][1]);
      C[p][2] = fmaf(w, c4.z, C[p][2]);
      An[p][0] = fmaf(al, c4.x, An[p][0]);
      An[p][1] = fmaf(al, c4.y, An[p][1]);
      An[p][2] = fmaf(al, c4.z, An[p][2]);
      S[p] += al;
    }
    m &= (m - 1ULL);
    i = j + 1;
  }

#pragma unroll
  for (int p = 0; p < 4; ++p) sS[seg][pslot][p] = S[p];
  __syncthreads();

  if (seg >= 1) {
#pragma unroll
    for (int p = 0; p < 4; ++p) {
      float Sp = sS[0][pslot][p];
      if (seg >= 2) Sp += sS[1][pslot][p];
      if (seg >= 3) Sp += sS[2][pslot][p];
      sD[seg - 1][pslot][p][0] = fmaf(-Sp, An[p][0] + Af[0], C[p][0]);
      sD[seg - 1][pslot][p][1] = fmaf(-Sp, An[p][1] + Af[1], C[p][1]);
      sD[seg - 1][pslot][p][2] = fmaf(-Sp, An[p][2] + Af[2], C[p][2]);
    }
  }
  __syncthreads();

  if (seg == 0) {
    int x = tx * TS + lx;
#pragma unroll
    for (int p = 0; p < 4; ++p) {
      int y = ty * TS + ly0 + p;
      size_t o = ((size_t)y * IMG_W + x) * 3;
      out[o + 0] = C[p][0] + sD[0][pslot][p][0] + sD[1][pslot][p][0] +
                   sD[2][pslot][p][0];
      out[o + 1] = C[p][1] + sD[0][pslot][p][1] + sD[1][pslot][p][1] +
                   sD[2][pslot][p][1];
      out[o + 2] = C[p][2] + sD[0][pslot][p][2] + sD[1][pslot][p][2] +
                   sD[2][pslot][p][2];
    }
  }
}

extern "C" void kernel_launch(void* const* d_in, const int* in_sizes, int n_in,
                              void* d_out, int out_size, void* d_ws,
                              size_t ws_size, hipStream_t stream) {
  const float* mu = (const float*)d_in[0];
  const float* cov = (const float*)d_in[1];
  const float* opacity = (const float*)d_in[2];
  const float* color = (const float*)d_in[3];
  const int* tile_idx = (const int*)d_in[4];
  float* out = (float*)d_out;
  (void)d_ws;
  (void)ws_size;

  render_all<<<T * 8, 512, 0, stream>>>(mu, cov, opacity, color, tile_idx,
                                        out);
}